// Round 7
// baseline (57.004 us; speedup 1.0000x reference)
//
#include <hip/hip_runtime.h>

// SimpleSNN: out[r][j] = sum over 10 steps of spikes from a leaky neuron driven by
// cur[r][j] = dot(x[r,:], W[j,:]).  x:[65536,784] f32, W:[10,784] f32, out f32.
//
// R7: no SMEM in the inner loop. R3==R6 (48.5/48.9us) falsified the vmcnt-depth
// theory; the invariant was s_load(W) mixing with ds_read(x) in lgkmcnt. SMEM
// returns OUT OF ORDER -> compiler must drain lgkmcnt(0) before each FMA block,
// and W64T (62.7KB) > K$ (16KB) -> s_loads miss to L2 (~300cy) every tile, all
// 8 barrier-locked waves stalling together. Fix:
//  - W converted once per block to f64 in LDS, transposed [c][j]. Wave-uniform
//    ds_read_b64 = free broadcast, in-order -> counted lgkmcnt, pipelined under
//    FMAs. No w_prep kernel, no SGPR pressure.
//  - x quad-buffered in LDS (4*4352B); TWO tiles per barrier period -> 25
//    barriers (was 49), and all 512 threads stage exactly one float4/period.
//  - register pair-pipeline: pB = pair t+2 (written to LDS this period),
//    pC = pair t+4 (issued this period) -> wlds waits on loads one full period
//    old, counted vmcnt.
//  - LDS total 80128B -> 2 blocks/CU (16 waves/CU). VALU floor ~14us; memory
//    floor ~16-25us (x partially L3-resident).
//  - f64 products/accum/recurrence, per-thread order bit-identical to R3/R6
//    (absmax==0 five rounds running; mem>1.0 crossings are the hazard).

constexpr int ROWS  = 65536;
constexpr int COLS  = 784;
constexpr int NOUT  = 10;
constexpr int STEPS = 10;

constexpr int BR   = 64;            // rows per block (thread r owns one row)
constexpr int TW   = 16;            // tile width (784 = 49*16)
constexpr int NT   = COLS / TW;     // 49 tiles
constexpr int PADW = 17;            // odd dword stride: 2 lanes/bank = free
constexpr int NH   = 8;             // column octants (= waves per block)
constexpr int CPH  = TW / NH;       // 2 cols per thread per tile

constexpr int XBUF_F  = BR * PADW;          // floats per x buffer (1088)
constexpr int W_OFF_B = 4 * XBUF_F * 4;     // 17408 B: x quad-buffer
constexpr int LDS_B   = W_OFF_B + NOUT * COLS * 8;  // 17408 + 62720 = 80128 B

__global__ __launch_bounds__(512, 4)
void snn_fused(const float* __restrict__ x, const float* __restrict__ W,
               float* __restrict__ out) {
    __shared__ __align__(16) char smem[LDS_B];
    float*  xb   = reinterpret_cast<float*>(smem);            // [4][BR][PADW]
    double* wl   = reinterpret_cast<double*>(smem + W_OFF_B); // [COLS][NOUT] f64
    double* comb = reinterpret_cast<double*>(smem);           // epilogue alias

    const int tid = threadIdx.x;
    const int r   = tid & 63;                                 // lane = row
    const int hu  = __builtin_amdgcn_readfirstlane(tid >> 6); // wave = col octant
    const size_t row0 = (size_t)blockIdx.x * BR;
    const float* xblk = x + row0 * COLS;

    // one-time: W f32 -> f64 LDS, transposed [c][j] (reads are L2-resident)
    for (int i = tid; i < NOUT * COLS; i += 512) {
        int c = i / NOUT, j = i - c * NOUT;
        wl[i] = (double)W[(size_t)j * COLS + c];
    }

    // staging: 512 threads, one float4 each per tile-PAIR
    const int s   = tid >> 8;          // which tile of the pair (0/1)
    const int idx = tid & 255;
    const int rr  = idx >> 2, c4 = idx & 3;

    auto issuePair = [&](int t0, float4& v) {
        int t = t0 + s;
        if (t < NT)
            v = *reinterpret_cast<const float4*>(xblk + (size_t)rr * COLS + t * TW + c4 * 4);
    };
    auto wldsPair = [&](int t0, const float4& v) {
        int t = t0 + s;
        if (t < NT) {
            float* p = xb + (t & 3) * XBUF_F + rr * PADW + c4 * 4;
            p[0] = v.x; p[1] = v.y; p[2] = v.z; p[3] = v.w;
        }
    };

    double acc[NOUT];
    #pragma unroll
    for (int j = 0; j < NOUT; ++j) acc[j] = 0.0;

    float4 pA, pB, pC;
    issuePair(0, pA); wldsPair(0, pA);    // tiles 0,1 -> LDS
    issuePair(2, pB);                     // tiles 2,3 -> regs
    __syncthreads();

    for (int p = 0; p < NT / 2; ++p) {    // 24 periods, tiles 0..47
        const int t = 2 * p;
        wldsPair(t + 2, pB);              // counted vmcnt: pC stays in flight
        issuePair(t + 4, pC);             // guards skip tiles >= 49

        #pragma unroll
        for (int u = 0; u < 2; ++u) {
            const int tt = t + u;
            const float*  src = xb + (tt & 3) * XBUF_F + r * PADW + hu * CPH;
            const double* wb  = wl + (size_t)(tt * TW + hu * CPH) * NOUT;
            #pragma unroll
            for (int c = 0; c < CPH; ++c) {
                double xd = (double)src[c];          // ds_read2_b32 + cvt
                #pragma unroll
                for (int j = 0; j < NOUT; ++j)       // ds_read_b64 broadcast + fma
                    acc[j] = fma(xd, wb[c * NOUT + j], acc[j]);
            }
        }
        __syncthreads();                  // one barrier per 2 tiles (25 total)
        pB = pC;                          // static rotation
    }

    // tail tile 48 (staged at p=23 via wldsPair(48,.), s==0 half)
    {
        const int tt = NT - 1;
        const float*  src = xb + (tt & 3) * XBUF_F + r * PADW + hu * CPH;
        const double* wb  = wl + (size_t)(tt * TW + hu * CPH) * NOUT;
        #pragma unroll
        for (int c = 0; c < CPH; ++c) {
            double xd = (double)src[c];
            #pragma unroll
            for (int j = 0; j < NOUT; ++j)
                acc[j] = fma(xd, wb[c * NOUT + j], acc[j]);
        }
    }
    __syncthreads();                      // before combine aliases xb/wl region

    // combine 8 octant-partials per (row, j), then run the recurrence
    #pragma unroll
    for (int j = 0; j < NOUT; ++j)
        comb[(hu * BR + r) * NOUT + j] = acc[j];
    __syncthreads();

    for (int i = tid; i < BR * NOUT; i += 512) {   // 640 outputs, 512 threads
        double c0 = comb[i]                  + comb[BR * NOUT + i];
        double c1 = comb[2 * BR * NOUT + i]  + comb[3 * BR * NOUT + i];
        double c2 = comb[4 * BR * NOUT + i]  + comb[5 * BR * NOUT + i];
        double c3 = comb[6 * BR * NOUT + i]  + comb[7 * BR * NOUT + i];
        double cur = (c0 + c1) + (c2 + c3);

        double mem = 0.0, spk = 0.0, sum = 0.0;
        #pragma unroll
        for (int st = 0; st < STEPS; ++st) {
            mem = 0.95 * mem + cur - spk;          // reset-by-subtraction, thr=1.0
            spk = (mem > 1.0) ? 1.0 : 0.0;
            sum += spk;
        }
        out[row0 * NOUT + i] = (float)sum;         // 2560B coalesced per block
    }
}

extern "C" void kernel_launch(void* const* d_in, const int* in_sizes, int n_in,
                              void* d_out, int out_size, void* d_ws, size_t ws_size,
                              hipStream_t stream) {
    const float* x = (const float*)d_in[0];
    const float* W = (const float*)d_in[1];
    float* out = (float*)d_out;
    hipLaunchKernelGGL(snn_fused, dim3(ROWS / BR), dim3(512), 0, stream, x, W, out);
}

// Round 9
// 49.634 us; speedup vs baseline: 1.1485x; 1.1485x over previous
//
#include <hip/hip_runtime.h>

// SimpleSNN: out[r][j] = sum over 10 steps of spikes from a leaky neuron driven by
// cur[r][j] = dot(x[r,:], W[j,:]).  x:[65536,784] f32, W:[10,784] f32, out f32.
//
// R9 = R3 skeleton with 4 tiles per barrier period (49 -> 12 periods + tail).
// Ledger: R3/R6 48.5 (baseline, depth irrelevant), R5 81 (70 W-doubles blew SGPR
// budget), R7 57 (W-in-LDS saturates LDS pipe), R4 68 (per-lane rows uncoalesced),
// R8 fail (f64 MFMA layout unverified). Surviving theory for R3's ~830cy/tile
// residual: fixed per-period cost (8-wave barrier skew + lgkm drain + ramp).
// This round cuts period count 4x while keeping every proven-safe element:
//  - W via wave-uniform s_load of pre-converted W64T, 20 doubles per tile body,
//    tile sub-loop `#pragma unroll 1` so the compiler cannot hoist 4 tiles of
//    s_loads into 160 SGPRs (the R5 failure).
//  - staging per period = 256B contiguous per row (16 lanes = 4 full lines),
//    8-buffer LDS ring (34.8KB), issue period P+2 / write P+1 / compute P.
//  - combine in TWO half-passes (20KB) so LDS union stays 34.8KB -> 4 blocks/CU
//    x 8 waves = 32 waves/CU.
//  - f64 products/accum/recurrence, per-thread order identical to R3 (absmax==0
//    across six rounds; mem>1.0 threshold crossings are the correctness hazard).

constexpr int ROWS  = 65536;
constexpr int COLS  = 784;
constexpr int NOUT  = 10;
constexpr int STEPS = 10;

constexpr int BR   = 64;           // rows per block (thread r owns one row)
constexpr int TW   = 16;           // tile width (784 = 49*16)
constexpr int NT   = COLS / TW;    // 49 tiles
constexpr int PADW = 17;           // odd dword stride -> conflict-free b32 reads
constexpr int NH   = 8;            // column octants (= waves per block)
constexpr int CPH  = TW / NH;      // 2 cols per thread per tile
constexpr int TPP  = 4;            // tiles per barrier period
constexpr int NP   = 12;           // full periods (tiles 0..47); tile 48 = tail
constexpr int NBUF = 8;            // LDS tile ring

constexpr int BUF_F = BR * PADW;   // 1088 floats per tile buffer

__global__ void w_prep(const float* __restrict__ W, double* __restrict__ W64T) {
    int i = blockIdx.x * 256 + threadIdx.x;   // i = c*10 + j
    if (i < NOUT * COLS) {
        int c = i / NOUT, j = i - c * NOUT;
        W64T[i] = (double)W[(size_t)j * COLS + c];
    }
}

__global__ __launch_bounds__(512, 8)
void snn_fused(const float* __restrict__ x, const double* __restrict__ W64T,
               float* __restrict__ out) {
    // union: 8 x-tile buffers (34816B)  /  comb [NH][32][NOUT] f64 (20480B)
    __shared__ __align__(16) char smem[NBUF * BUF_F * 4];
    float*  bufs = reinterpret_cast<float*>(smem);
    double* comb = reinterpret_cast<double*>(smem);

    const int tid = threadIdx.x;
    const int r   = tid & 63;                                  // lane = row
    const int hu  = __builtin_amdgcn_readfirstlane(tid >> 6);  // wave = col octant
    const size_t row0 = (size_t)blockIdx.x * BR;
    const float* xblk = x + row0 * COLS;

    // staging: period P = 4 tiles = 64 rows x 256B; slot s: row=s>>4, seg=s&15.
    // 16 consecutive lanes cover one row's 256B (4 full lines) -> ideal coalescing.
    auto issueP = [&](int P, float4* v) {
        #pragma unroll
        for (int k = 0; k < 2; ++k) {
            int s = tid + 512 * k;
            int row = s >> 4, seg = s & 15;
            int t  = P * TPP + (seg >> 2);
            int tc = (t < NT) ? t : NT - 1;      // clamp: dup loads are benign
            v[k] = *reinterpret_cast<const float4*>(
                xblk + (size_t)row * COLS + tc * TW + (seg & 3) * 4);
        }
    };
    auto wldsP = [&](int P, const float4* v) {
        #pragma unroll
        for (int k = 0; k < 2; ++k) {
            int s = tid + 512 * k;
            int row = s >> 4, seg = s & 15;
            int t  = P * TPP + (seg >> 2);
            int tc = (t < NT) ? t : NT - 1;      // dup writes: same addr, same value
            float* p = bufs + (tc & (NBUF - 1)) * BUF_F + row * PADW + (seg & 3) * 4;
            p[0] = v[k].x; p[1] = v[k].y; p[2] = v[k].z; p[3] = v[k].w;
        }
    };

    double acc[NOUT];
    #pragma unroll
    for (int j = 0; j < NOUT; ++j) acc[j] = 0.0;

    float4 v0[2], v1[2];
    issueP(0, v0); wldsP(0, v0);      // tiles 0..3 -> LDS
    issueP(1, v1);                    // tiles 4..7 -> regs (in flight)
    __syncthreads();

    for (int p = 0; p < NP; ++p) {
        wldsP(p + 1, v1);             // counted vmcnt; flight ~1 full period
        if (p + 2 <= NP) issueP(p + 2, v0);

        #pragma unroll 1              // keep W at 20 live doubles (R5 lesson)
        for (int u = 0; u < TPP; ++u) {
            const int tt = p * TPP + u;
            const float*  src = bufs + (tt & (NBUF - 1)) * BUF_F + r * PADW + hu * CPH;
            const double* wb  = W64T + (size_t)(tt * TW + hu * CPH) * NOUT;
            #pragma unroll
            for (int c = 0; c < CPH; ++c) {
                double xd = (double)src[c];          // ds_read, conflict-free (17)
                #pragma unroll
                for (int j = 0; j < NOUT; ++j)
                    acc[j] = fma(xd, wb[c * NOUT + j], acc[j]);
            }
        }
        __syncthreads();              // ONE barrier per 4 tiles
        v1[0] = v0[0]; v1[1] = v0[1];
    }

    // tail: tile 48 (staged by the p=11 wldsP(12) with clamped dups)
    {
        const int tt = NT - 1;
        const float*  src = bufs + (tt & (NBUF - 1)) * BUF_F + r * PADW + hu * CPH;
        const double* wb  = W64T + (size_t)(tt * TW + hu * CPH) * NOUT;
        #pragma unroll
        for (int c = 0; c < CPH; ++c) {
            double xd = (double)src[c];
            #pragma unroll
            for (int j = 0; j < NOUT; ++j)
                acc[j] = fma(xd, wb[c * NOUT + j], acc[j]);
        }
    }

    // combine in two half-passes (comb aliases bufs -> 20KB instead of 40KB)
    #pragma unroll 1
    for (int half = 0; half < 2; ++half) {
        __syncthreads();                         // protect aliased region
        if ((r >> 5) == half) {
            #pragma unroll
            for (int j = 0; j < NOUT; ++j)
                comb[(hu * 32 + (r & 31)) * NOUT + j] = acc[j];
        }
        __syncthreads();
        for (int i = tid; i < 32 * NOUT; i += 512) {   // 320 outputs
            double c0 = comb[i]                  + comb[32 * NOUT + i];
            double c1 = comb[2 * 32 * NOUT + i]  + comb[3 * 32 * NOUT + i];
            double c2 = comb[4 * 32 * NOUT + i]  + comb[5 * 32 * NOUT + i];
            double c3 = comb[6 * 32 * NOUT + i]  + comb[7 * 32 * NOUT + i];
            double cur = (c0 + c1) + (c2 + c3);

            double mem = 0.0, spk = 0.0, s = 0.0;
            #pragma unroll
            for (int st = 0; st < STEPS; ++st) {
                mem = 0.95 * mem + cur - spk;    // reset-by-subtraction, thr=1.0
                spk = (mem > 1.0) ? 1.0 : 0.0;
                s  += spk;
            }
            out[(row0 + half * 32) * NOUT + i] = (float)s;
        }
    }
}

extern "C" void kernel_launch(void* const* d_in, const int* in_sizes, int n_in,
                              void* d_out, int out_size, void* d_ws, size_t ws_size,
                              hipStream_t stream) {
    const float* x = (const float*)d_in[0];
    const float* W = (const float*)d_in[1];
    float*  out  = (float*)d_out;
    double* W64T = (double*)d_ws;   // 7840 * 8B = 62.7 KB

    hipLaunchKernelGGL(w_prep, dim3((NOUT * COLS + 255) / 256), dim3(256), 0, stream, W, W64T);
    hipLaunchKernelGGL(snn_fused, dim3(ROWS / BR), dim3(512), 0, stream, x, W64T, out);
}